// Round 10
// baseline (342.752 us; speedup 1.0000x reference)
//
#include <hip/hip_runtime.h>
#include <math.h>

typedef short bf16x8 __attribute__((ext_vector_type(8)));
typedef float f32x4  __attribute__((ext_vector_type(4)));

__device__ __forceinline__ unsigned short f2bf(float f) {
    unsigned int u = __builtin_bit_cast(unsigned int, f);
    u += 0x7FFFu + ((u >> 16) & 1u);
    return (unsigned short)(u >> 16);
}
__device__ __forceinline__ float bf2f(unsigned short u) {
    return __builtin_bit_cast(float, (unsigned int)u << 16);
}
// pack two f32 -> two bf16 (truncating) in one v_perm
__device__ __forceinline__ unsigned pktrunc(float hi, float lo) {
    return __builtin_amdgcn_perm(__builtin_bit_cast(unsigned, hi),
                                 __builtin_bit_cast(unsigned, lo), 0x07060302u);
}

// async global->LDS, 16B per lane. LDS dest = wave-uniform base + lane*16;
// source address may be arbitrary per-lane (we exploit this for swizzles).
__device__ __forceinline__ void gld16(const unsigned short* g, unsigned short* l) {
    __builtin_amdgcn_global_load_lds(
        (const __attribute__((address_space(1))) void*)g,
        (__attribute__((address_space(3))) void*)l, 16, 0, 0);
}

#define QSCALE 0.18033688011112042f   // 0.125 * log2(e)

// ---------------------------------------------------------------------------
// prep: fused cast3 + weight transposes (+Wo column permute) + mask pack.
// ---------------------------------------------------------------------------
__global__ __launch_bounds__(256) void prep(
    const float* __restrict__ x, const float* __restrict__ c1, const float* __restrict__ c2,
    const int* __restrict__ mask1, const int* __restrict__ mask2,
    const float* __restrict__ Wq, const float* __restrict__ Wk1, const float* __restrict__ Wk2,
    const float* __restrict__ Wv1, const float* __restrict__ Wv2, const float* __restrict__ Wo,
    unsigned short* __restrict__ xb, unsigned short* __restrict__ c1b, unsigned short* __restrict__ c2b,
    unsigned short* __restrict__ Wqt, unsigned short* __restrict__ Wk1t, unsigned short* __restrict__ Wk2t,
    unsigned short* __restrict__ Wv1t, unsigned short* __restrict__ Wv2t, unsigned short* __restrict__ Wot,
    unsigned long long* __restrict__ mpk)
{
    __shared__ float T[64][65];
    const int bid = blockIdx.x, t = threadIdx.x;

    if (bid < 3072) {                                   // cast fp32->bf16
        const int z = bid >> 10;
        const float* a = z == 0 ? x : (z == 1 ? c1 : c2);
        unsigned short* o = z == 0 ? xb : (z == 1 ? c1b : c2b);
        size_t i = ((size_t)(bid & 1023) * 256 + t) * 8;
        float4 x0 = *(const float4*)&a[i];
        float4 x1 = *(const float4*)&a[i + 4];
        uint4 pk;
        pk.x = (unsigned)f2bf(x0.x) | ((unsigned)f2bf(x0.y) << 16);
        pk.y = (unsigned)f2bf(x0.z) | ((unsigned)f2bf(x0.w) << 16);
        pk.z = (unsigned)f2bf(x1.x) | ((unsigned)f2bf(x1.y) << 16);
        pk.w = (unsigned)f2bf(x1.z) | ((unsigned)f2bf(x1.w) << 16);
        *(uint4*)&o[i] = pk;
        return;
    }
    if (bid < 4224) {                                   // weight cast+transpose
        const float* W; unsigned short* O; int N, n0, k0; bool perm = false;
        if (bid < 3456) {
            int l = bid - 3072, z = l >> 7, rem = l & 127;
            W = z == 0 ? Wq : (z == 1 ? Wk1 : Wk2);
            O = z == 0 ? Wqt : (z == 1 ? Wk1t : Wk2t);
            N = 512; n0 = (rem & 7) << 6; k0 = (rem >> 3) << 6;
        } else {
            int l = bid - 3456, z = l >> 8, rem = l & 255;
            W = z == 0 ? Wv1 : (z == 1 ? Wv2 : Wo);
            O = z == 0 ? Wv1t : (z == 1 ? Wv2t : Wot);
            N = 1024; n0 = (rem & 15) << 6; k0 = (rem >> 4) << 6;
            perm = (z == 2);
        }
        #pragma unroll
        for (int i = 0; i < 4; i++) {
            int vi = t + (i << 8);
            int r = vi >> 4, c4 = (vi & 15) << 2;
            *(float4*)&T[r][c4] = *(const float4*)&W[(size_t)(k0 + r) * N + n0 + c4];
        }
        __syncthreads();
        #pragma unroll
        for (int i = 0; i < 4; i++) {
            int vi = t + (i << 8);
            int n = vi >> 4, k4 = (vi & 15) << 2;
            if (!perm) {
                uint2 pk;
                pk.x = (unsigned)f2bf(T[k4 + 0][n]) | ((unsigned)f2bf(T[k4 + 1][n]) << 16);
                pk.y = (unsigned)f2bf(T[k4 + 2][n]) | ((unsigned)f2bf(T[k4 + 3][n]) << 16);
                *(uint2*)&O[(size_t)(n0 + n) * 1024 + k0 + k4] = pk;
            } else {
                #pragma unroll
                for (int ii = 0; ii < 4; ii++) {
                    int k = k0 + k4 + ii, f = k & 127;
                    int kp = (k & ~127) | ((f & 15) << 3) | (f >> 4);   // head f-permute
                    O[(size_t)(n0 + n) * 1024 + kp] = f2bf(T[k4 + ii][n]);
                }
            }
        }
        return;
    }
    {                                                   // mask pack
        int wid = ((bid - 4224) << 2) + (t >> 6);
        int lane = t & 63;
        const int* m1 = mask1 + ((size_t)wid << 10);
        const int* m2 = mask2 + ((size_t)wid << 10);
        unsigned long long* o = mpk + ((size_t)wid << 5);
        #pragma unroll
        for (int win = 0; win < 16; win++) {
            unsigned long long bal = __ballot(m1[(win << 6) + lane] != 0);
            if (lane == 0) o[win] = bal;
        }
        #pragma unroll
        for (int win = 0; win < 16; win++) {
            unsigned long long bal = __ballot(m2[(win << 6) + lane] != 0);
            if (lane == 0) o[16 + win] = bal;
        }
    }
}

// ---------------------------------------------------------------------------
// MFMA GEMM core, BK=64, source-permuted gld16 staging (chunk ^= row&7) so
// LDS dest stays linear but frag ds_read_b128s are conflict-free.
// Templated on M-tile and N-tile (waves in 2x2).
// ---------------------------------------------------------------------------
template<int MT, int NT>
__device__ __forceinline__ void gemm_core64(
    const unsigned short* __restrict__ A,
    const unsigned short* __restrict__ Wt,
    int K, int gm0, int gn0,
    unsigned short* As, unsigned short* Bs,
    f32x4 (&acc)[MT / 32][NT / 32])
{
    const int t = threadIdx.x;
    const int lane = t & 63, w = t >> 6;
    const int wm = (w & 1) * (MT / 2), wn = (w >> 1) * (NT / 2);
    const int l15 = lane & 15, quad = lane >> 4;
    const int lrow = lane >> 3, lchk = lane & 7;

    for (int k0 = 0; k0 < K; k0 += 64) {
        __syncthreads();
        #pragma unroll
        for (int i = 0; i < MT / 32; i++) {         // A: MT x 64
            int r0 = w * (MT / 4) + (i << 3);
            int ra = r0 + lrow;
            int kc = (lchk ^ (ra & 7)) << 3;
            gld16(&A[(size_t)(gm0 + ra) * K + k0 + kc], As + (r0 << 6) + (lane << 3));
        }
        #pragma unroll
        for (int i = 0; i < NT / 32; i++) {         // B: NT x 64
            int r0 = w * (NT / 4) + (i << 3);
            int ra = r0 + lrow;
            int kc = (lchk ^ (ra & 7)) << 3;
            gld16(&Wt[(size_t)(gn0 + ra) * K + k0 + kc], Bs + (r0 << 6) + (lane << 3));
        }
        __syncthreads();
        #pragma unroll
        for (int kk = 0; kk < 2; kk++) {
            bf16x8 af[MT / 32], bg[NT / 32];
            #pragma unroll
            for (int i = 0; i < MT / 32; i++) {
                int row = wm + (i << 4) + l15;
                af[i] = *(const bf16x8*)&As[(row << 6) + ((((kk << 2) + quad) ^ (row & 7)) << 3)];
            }
            #pragma unroll
            for (int j = 0; j < NT / 32; j++) {
                int row = wn + (j << 4) + l15;
                bg[j] = *(const bf16x8*)&Bs[(row << 6) + ((((kk << 2) + quad) ^ (row & 7)) << 3)];
            }
            #pragma unroll
            for (int i = 0; i < MT / 32; i++)
                #pragma unroll
                for (int j = 0; j < NT / 32; j++)
                    acc[i][j] = __builtin_amdgcn_mfma_f32_16x16x32_bf16(af[i], bg[j], acc[i][j], 0, 0, 0);
        }
    }
}

// ---------------------------------------------------------------------------
// All 5 projections. qbuf pre-scaled by 0.125*log2e. k/v epilogues transpose
// through LDS so all global stores are coalesced uint4.
// ---------------------------------------------------------------------------
__global__ __launch_bounds__(256) void proj_all(
    const unsigned short* __restrict__ xb, const unsigned short* __restrict__ c1b,
    const unsigned short* __restrict__ c2b,
    const unsigned short* __restrict__ Wqt, const unsigned short* __restrict__ Wk1t,
    const unsigned short* __restrict__ Wk2t, const unsigned short* __restrict__ Wv1t,
    const unsigned short* __restrict__ Wv2t,
    const float* __restrict__ bq, const float* __restrict__ bk1, const float* __restrict__ bk2,
    const float* __restrict__ bv1, const float* __restrict__ bv2,
    unsigned short* __restrict__ qbuf, unsigned short* __restrict__ khb,
    unsigned short* __restrict__ vhb)
{
    __shared__ unsigned short smem[17408];   // As 8192 + Bs 8192; Ts 17408 (union)
    unsigned short* As = smem;
    unsigned short* Bs = smem + 8192;
    unsigned short* Ts = smem;               // [128][136] after core

    const int bid = blockIdx.x;
    int z, bx, by;
    if (bid < 192) { z = bid >> 6; int l = bid & 63; by = l >> 2; bx = l & 3; }
    else { int l = bid - 192; z = 3 + (l >> 7); l &= 127; by = l >> 3; bx = l & 7; }
    const unsigned short* A  = (z == 0) ? xb : (z == 1 || z == 3) ? c1b : c2b;
    const unsigned short* Wt = (z == 0) ? Wqt : (z == 1) ? Wk1t : (z == 2) ? Wk2t
                             : (z == 3) ? Wv1t : Wv2t;
    const float* bias = (z == 0) ? bq : (z == 1) ? bk1 : (z == 2) ? bk2
                      : (z == 3) ? bv1 : bv2;
    const int gm0 = by << 7, gn0 = bx << 7;

    f32x4 acc[4][4];
    #pragma unroll
    for (int i = 0; i < 4; i++)
        #pragma unroll
        for (int j = 0; j < 4; j++) acc[i][j] = (f32x4){0.f, 0.f, 0.f, 0.f};

    gemm_core64<128, 128>(A, Wt, 1024, gm0, gn0, As, Bs, acc);

    const int t = threadIdx.x;
    const int lane = t & 63, w = t >> 6;
    const int wm = (w & 1) << 6, wn = (w >> 1) << 6;
    const int l15 = lane & 15, quad = lane >> 4;
    float bb[4];
    #pragma unroll
    for (int j = 0; j < 4; j++) bb[j] = bias[gn0 + wn + (j << 4) + l15];

    if (z == 0) {                                       // q: row-major, scale baked
        #pragma unroll
        for (int i = 0; i < 4; i++) {
            int mb = gm0 + wm + (i << 4) + (quad << 2);
            #pragma unroll
            for (int p = 0; p < 4; p++)
                #pragma unroll
                for (int j = 0; j < 4; j++)
                    qbuf[(size_t)(mb + p) * 512 + gn0 + wn + (j << 4) + l15]
                        = f2bf((acc[i][j][p] + bb[j]) * QSCALE);
        }
        return;
    }

    __syncthreads();                                    // staging LDS dead -> Ts
    const int b = gm0 >> 10;
    if (z < 3) {                                        // k -> khb[b][h][j][64] swz
        const int jb = ((z == 2) ? 1024 : 0) + (gm0 & 1023);
        #pragma unroll
        for (int i = 0; i < 4; i++) {
            int jl0 = wm + (i << 4) + (quad << 2);
            #pragma unroll
            for (int j = 0; j < 4; j++) {
                int n = wn + (j << 4) + l15;
                #pragma unroll
                for (int p = 0; p < 4; p++)
                    Ts[(jl0 + p) * 136 + n] = f2bf(acc[i][j][p] + bb[j]);
            }
        }
        __syncthreads();
        #pragma unroll
        for (int rr = 0; rr < 8; rr++) {
            int row = (rr << 4) + (t >> 4), cd = t & 15;
            uint4 v = *(const uint4*)&Ts[row * 136 + (cd << 3)];
            int jg = jb + row;
            int hcol = (gn0 >> 6) + (cd >> 3);
            size_t hb = ((size_t)((b << 3) + hcol) << 17);
            *(uint4*)&khb[hb + ((size_t)jg << 6) + ((((cd & 7) ^ (jg & 7))) << 3)] = v;
        }
    } else {                                            // v -> vhb[b][h][f][2048] swz
        const int jb = ((z == 3) ? 0 : 1024) + (gm0 & 1023);
        #pragma unroll
        for (int i = 0; i < 4; i++) {
            int jl0 = wm + (i << 4) + (quad << 2);
            #pragma unroll
            for (int j = 0; j < 4; j++) {
                int n = wn + (j << 4) + l15;
                unsigned long long pk = 0;
                #pragma unroll
                for (int p = 0; p < 4; p++)
                    pk |= (unsigned long long)f2bf(acc[i][j][p] + bb[j]) << (16 * p);
                *(unsigned long long*)&Ts[n * 136 + jl0] = pk;
            }
        }
        __syncthreads();
        const int hv = gn0 >> 7;
        size_t hbase = ((size_t)((b << 3) + hv) << 18);
        #pragma unroll
        for (int rr = 0; rr < 8; rr++) {
            int f = (rr << 4) + (t >> 4), cj = t & 15;
            uint4 v = *(const uint4*)&Ts[f * 136 + (cj << 3)];
            int jj = jb + (cj << 3);
            int jpos = (jj & ~63) | ((((jj >> 3) & 7) ^ (f & 7)) << 3);
            *(uint4*)&vhb[hbase + ((size_t)f << 11) + jpos] = v;
        }
    }
}

// ---------------------------------------------------------------------------
// final: out = abuf(bf16, f'-permuted cols) @ Wot(perm-baked)^T + bo, fp32.
// 64x64 tiles -> 512 blocks = 2 blocks/CU (was 256 = 1/CU, latency-exposed).
// ---------------------------------------------------------------------------
__global__ __launch_bounds__(256) void gemm_out(
    const unsigned short* __restrict__ abuf, const unsigned short* __restrict__ Wot,
    const float* __restrict__ bo, float* __restrict__ out)
{
    __shared__ unsigned short smem[8192];    // As 4096 + Bs 4096
    unsigned short* As = smem;
    unsigned short* Bs = smem + 4096;
    const int gm0 = blockIdx.y << 6, gn0 = blockIdx.x << 6;

    f32x4 acc[2][2];
    #pragma unroll
    for (int i = 0; i < 2; i++)
        #pragma unroll
        for (int j = 0; j < 2; j++) acc[i][j] = (f32x4){0.f, 0.f, 0.f, 0.f};

    gemm_core64<64, 64>(abuf, Wot, 1024, gm0, gn0, As, Bs, acc);

    const int lane = threadIdx.x & 63, w = threadIdx.x >> 6;
    const int wm = (w & 1) << 5, wn = (w >> 1) << 5;
    const int l15 = lane & 15, quad = lane >> 4;
    float bb[2];
    #pragma unroll
    for (int j = 0; j < 2; j++) bb[j] = bo[gn0 + wn + (j << 4) + l15];
    #pragma unroll
    for (int i = 0; i < 2; i++) {
        int mb = gm0 + wm + (i << 4) + (quad << 2);
        #pragma unroll
        for (int p = 0; p < 4; p++)
            #pragma unroll
            for (int j = 0; j < 2; j++)
                out[(size_t)(mb + p) * 1024 + gn0 + wn + (j << 4) + l15] = acc[i][j][p] + bb[j];
    }
}

// ---------------------------------------------------------------------------
// MFMA flash attention with fused j-split combine (last-block-done, FREE
// register allocation — r8's regression was the launch_bounds VGPR cap).
// 1024 blocks = (jsplit4, b, qt16, h). j-tile 64, 16 q-rows/wave.
// ---------------------------------------------------------------------------
__global__ __launch_bounds__(256) void attn_mfma(
    const unsigned short* __restrict__ qbuf, const unsigned short* __restrict__ khb,
    const unsigned short* __restrict__ vhb, const unsigned long long* __restrict__ mpk,
    unsigned short* __restrict__ Opart, float* __restrict__ ml,
    int* __restrict__ cnt, unsigned short* __restrict__ abuf)
{
    __shared__ unsigned short Ks[64 * 64];     // 8 KB
    __shared__ unsigned short VsT[128 * 64];   // 16 KB
    __shared__ unsigned short Ps[64 * 64];     // 8 KB
    __shared__ int winner_sh;

    const int t = threadIdx.x;
    const int bid = blockIdx.x;
    const int hs = bid >> 8, r = bid & 255;
    const int h = r & 7, qt = (r >> 3) & 15, b = r >> 7;
    const int q0 = qt << 6;
    const int lane = t & 63, w = t >> 6, l15 = lane & 15, quad = lane >> 4;
    const int v7 = l15 & 7;

    const unsigned short* qrow = qbuf + (((size_t)(b << 10) + q0 + (w << 4) + l15) << 9) + (h << 6);
    const bf16x8 aq0 = *(const bf16x8*)&qrow[quad << 3];
    const bf16x8 aq1 = *(const bf16x8*)&qrow[32 + (quad << 3)];

    f32x4 acc[8];
    #pragma unroll
    for (int ct = 0; ct < 8; ct++) acc[ct] = (f32x4){0.f, 0.f, 0.f, 0.f};
    float m_l = -3.0e38f, l_l = 0.f;

    const unsigned short* kh = khb + ((size_t)((b << 3) + h) << 17);
    const unsigned short* vh = vhb + ((size_t)((b << 3) + h) << 18);
    const unsigned long long* mrow = mpk + (((size_t)(b << 10) + q0 + (w << 4) + l15) << 5) + (hs << 3);
    const int prow = ((w << 4) + l15) << 6;

    for (int jt = 0; jt < 8; jt++) {
        const int j0 = (hs << 9) + (jt << 6);
        __syncthreads();
        {   // K tile: 8KB contiguous
            const unsigned short* kg = kh + ((size_t)j0 << 6);
            int o = (w << 10) + (lane << 3);
            gld16(kg + o, Ks + o);
            gld16(kg + o + 512, Ks + o + 512);
        }
        #pragma unroll
        for (int it = 0; it < 4; it++) {    // V tile: 128f x 64j
            int f0 = (w << 5) + (it << 3);
            gld16(vh + ((size_t)(f0 + (lane >> 3)) << 11) + j0 + ((lane & 7) << 3),
                  VsT + (f0 << 6) + (lane << 3));
        }
        __syncthreads();

        const unsigned long long mw = mrow[jt];

        // S^T = K Q^T (base-2 domain; scale baked in qbuf)
        f32x4 s[4];
        #pragma unroll
        for (int n = 0; n < 4; n++) {
            int rowk = (n << 4) + l15;
            bf16x8 bk0 = *(const bf16x8*)&Ks[(rowk << 6) + ((quad ^ v7) << 3)];
            bf16x8 bk1 = *(const bf16x8*)&Ks[(rowk << 6) + (((quad + 4) ^ v7) << 3)];
            s[n] = (f32x4){0.f, 0.f, 0.f, 0.f};
            s[n] = __builtin_amdgcn_mfma_f32_16x16x32_bf16(bk0, aq0, s[n], 0, 0, 0);
            s[n] = __builtin_amdgcn_mfma_f32_16x16x32_bf16(bk1, aq1, s[n], 0, 0, 0);
        }
        #pragma unroll
        for (int n = 0; n < 4; n++)
            #pragma unroll
            for (int p = 0; p < 4; p++)
                s[n][p] = ((mw >> ((n << 4) + (quad << 2) + p)) & 1ull) ? s[n][p] : -3.0e38f;

        float mt = s[0][0];
        #pragma unroll
        for (int n = 0; n < 4; n++)
            #pragma unroll
            for (int p = 0; p < 4; p++) mt = fmaxf(mt, s[n][p]);
        mt = fmaxf(mt, __shfl_xor(mt, 16, 64));
        mt = fmaxf(mt, __shfl_xor(mt, 32, 64));
        float mn = fmaxf(m_l, mt);
        float ls = 0.f;
        #pragma unroll
        for (int n = 0; n < 4; n++) {
            float e0 = __builtin_amdgcn_exp2f(s[n][0] - mn);
            float e1 = __builtin_amdgcn_exp2f(s[n][1] - mn);
            float e2 = __builtin_amdgcn_exp2f(s[n][2] - mn);
            float e3 = __builtin_amdgcn_exp2f(s[n][3] - mn);
            ls += (e0 + e1) + (e2 + e3);
            uint2 pk;
            pk.x = pktrunc(e1, e0);
            pk.y = pktrunc(e3, e2);
            int mblk = ((n << 1) + (quad >> 1)) ^ v7;
            *(uint2*)&Ps[prow + (mblk << 3) + ((quad & 1) << 2)] = pk;
        }
        ls += __shfl_xor(ls, 16, 64);
        ls += __shfl_xor(ls, 32, 64);
        float al = __builtin_amdgcn_exp2f(m_l - mn);
        l_l = l_l * al + ls;
        m_l = mn;

        float ar[4];
        #pragma unroll
        for (int p = 0; p < 4; p++)
            ar[p] = __shfl(al, (lane & 48) | ((quad << 2) + p), 64);
        #pragma unroll
        for (int ct = 0; ct < 8; ct++)
            #pragma unroll
            for (int p = 0; p < 4; p++) acc[ct][p] *= ar[p];

        // O += P V
        bf16x8 ap[2];
        #pragma unroll
        for (int win = 0; win < 2; win++) {
            int mblk = ((win << 2) + quad) ^ v7;
            ap[win] = *(const bf16x8*)&Ps[prow + (mblk << 3)];
        }
        #pragma unroll
        for (int ct = 0; ct < 8; ct++) {
            int f = (ct << 4) + l15;
            #pragma unroll
            for (int win = 0; win < 2; win++) {
                int c = (win << 2) + quad;
                bf16x8 bv = *(const bf16x8*)&VsT[(f << 6) + ((c ^ v7) << 3)];
                acc[ct] = __builtin_amdgcn_mfma_f32_16x16x32_bf16(ap[win], bv, acc[ct], 0, 0, 0);
            }
        }
    }

    const size_t bh10 = (size_t)((b << 3) + h) << 10;
    #pragma unroll
    for (int p = 0; p < 4; p++) {
        int q = q0 + (w << 4) + (quad << 2) + p;
        size_t idx = ((size_t)hs << 14) + bh10 + q;
        uint4 pk;
        pk.x = (unsigned)f2bf(acc[0][p]) | ((unsigned)f2bf(acc[1][p]) << 16);
        pk.y = (unsigned)f2bf(acc[2][p]) | ((unsigned)f2bf(acc[3][p]) << 16);
        pk.z = (unsigned)f2bf(acc[4][p]) | ((unsigned)f2bf(acc[5][p]) << 16);
        pk.w = (unsigned)f2bf(acc[6][p]) | ((unsigned)f2bf(acc[7][p]) << 16);
        *(uint4*)&Opart[(idx << 7) + (l15 << 3)] = pk;
    }
    if (quad == 0) {
        int q = q0 + (w << 4) + l15;
        size_t idx = ((size_t)hs << 14) + bh10 + q;
        ml[(idx << 1) + 0] = m_l;
        ml[(idx << 1) + 1] = l_l;
    }

    // last-block-done combine (release: device fence + device-scope atomic)
    __threadfence();
    __syncthreads();
    if (t == 0) winner_sh = (atomicAdd(&cnt[r], 1) == 3) ? 1 : 0;
    __syncthreads();
    if (!winner_sh) return;
    __threadfence();                                    // acquire

    #pragma unroll
    for (int it = 0; it < 8; it++) {
        int id = (it << 8) + t;                         // 0..2047 = 64q x 32c
        int q = q0 + (id >> 5), c = id & 31;
        size_t idx0 = bh10 + q;
        float2 m0 = *(const float2*)&ml[(idx0)         << 1];
        float2 m1 = *(const float2*)&ml[(idx0 + 16384) << 1];
        float2 m2 = *(const float2*)&ml[(idx0 + 32768) << 1];
        float2 m3 = *(const float2*)&ml[(idx0 + 49152) << 1];
        float M = fmaxf(fmaxf(m0.x, m1.x), fmaxf(m2.x, m3.x));
        float a0 = __builtin_amdgcn_exp2f(m0.x - M), a1 = __builtin_amdgcn_exp2f(m1.x - M);
        float a2 = __builtin_amdgcn_exp2f(m2.x - M), a3 = __builtin_amdgcn_exp2f(m3.x - M);
        float inv = 1.0f / (m0.y * a0 + m1.y * a1 + m2.y * a2 + m3.y * a3);
        float as[4] = {a0 * inv, a1 * inv, a2 * inv, a3 * inv};
        float o[4] = {0.f, 0.f, 0.f, 0.f};
        #pragma unroll
        for (int s2 = 0; s2 < 4; s2++) {
            uint2 v = *(const uint2*)&Opart[((idx0 + (size_t)s2 * 16384) << 7) + (c << 2)];
            o[0] += as[s2] * bf2f((unsigned short)(v.x & 0xFFFF));
            o[1] += as[s2] * bf2f((unsigned short)(v.x >> 16));
            o[2] += as[s2] * bf2f((unsigned short)(v.y & 0xFFFF));
            o[3] += as[s2] * bf2f((unsigned short)(v.y >> 16));
        }
        unsigned long long pk = (unsigned long long)f2bf(o[0])
            | ((unsigned long long)f2bf(o[1]) << 16)
            | ((unsigned long long)f2bf(o[2]) << 32)
            | ((unsigned long long)f2bf(o[3]) << 48);
        *(unsigned long long*)&abuf[((size_t)((b << 10) + q) << 10) + (h << 7) + (c << 2)] = pk;
    }
}

// ---------------------------------------------------------------------------
extern "C" void kernel_launch(void* const* d_in, const int* in_sizes, int n_in,
                              void* d_out, int out_size, void* d_ws, size_t ws_size,
                              hipStream_t stream)
{
    const float* x        = (const float*)d_in[0];
    const float* context  = (const float*)d_in[1];
    const float* context2 = (const float*)d_in[2];
    const int*   mask1    = (const int*)d_in[3];
    const int*   mask2    = (const int*)d_in[4];
    const float* Wq  = (const float*)d_in[5];
    const float* bq  = (const float*)d_in[6];
    const float* Wk1 = (const float*)d_in[7];
    const float* bk1 = (const float*)d_in[8];
    const float* Wv1 = (const float*)d_in[9];
    const float* bv1 = (const float*)d_in[10];
    const float* Wk2 = (const float*)d_in[11];
    const float* bk2 = (const float*)d_in[12];
    const float* Wv2 = (const float*)d_in[13];
    const float* bv2 = (const float*)d_in[14];
    const float* Wo  = (const float*)d_in[15];
    const float* bo  = (const float*)d_in[16];
    float* out = (float*)d_out;

    // Workspace (MB): Wot[0,2) xb[2,6) c1b[6,10) c2b[10,14) Wqt[14,15)
    // Wk1t[15,16) Wk2t[16,17) Wv1t[17,19) Wv2t[19,21) qbuf[21,23) khb[23,27)
    // vhb[27,35) mpk[35,35.5) mlb[35.5,36) cnt[36,36+1K).
    // Post-proj overlap: Opart[2,18), abuf[19,23).
    char* W = (char*)d_ws;
    unsigned short* Wot  = (unsigned short*)(W);
    unsigned short* xb   = (unsigned short*)(W + (2ull  << 20));
    unsigned short* c1b  = (unsigned short*)(W + (6ull  << 20));
    unsigned short* c2b  = (unsigned short*)(W + (10ull << 20));
    unsigned short* Wqt  = (unsigned short*)(W + (14ull << 20));
    unsigned short* Wk1t = (unsigned short*)(W + (15ull << 20));
    unsigned short* Wk2t = (unsigned short*)(W + (16ull << 20));
    unsigned short* Wv1t = (unsigned short*)(W + (17ull << 20));
    unsigned short* Wv2t = (unsigned short*)(W + (19ull << 20));
    unsigned short* qbuf = (unsigned short*)(W + (21ull << 20));
    unsigned short* khb  = (unsigned short*)(W + (23ull << 20));
    unsigned short* vhb  = (unsigned short*)(W + (27ull << 20));
    unsigned long long* mpk = (unsigned long long*)(W + (35ull << 20));
    float*          mlb  = (float*)(W + (35ull << 20) + (1ull << 19));
    int*            cnt  = (int*)(W + (36ull << 20));
    unsigned short* Opart = (unsigned short*)(W + (2ull << 20));
    unsigned short* abuf  = (unsigned short*)(W + (19ull << 20));

    hipMemsetAsync(cnt, 0, 1024, stream);
    prep<<<dim3(4736), 256, 0, stream>>>(x, context, context2, mask1, mask2,
                                         Wq, Wk1, Wk2, Wv1, Wv2, Wo,
                                         xb, c1b, c2b, Wqt, Wk1t, Wk2t, Wv1t, Wv2t, Wot, mpk);
    proj_all<<<dim3(448), 256, 0, stream>>>(xb, c1b, c2b, Wqt, Wk1t, Wk2t, Wv1t, Wv2t,
                                            bq, bk1, bk2, bv1, bv2, qbuf, khb, vhb);
    attn_mfma<<<dim3(1024), 256, 0, stream>>>(qbuf, khb, vhb, mpk, Opart, mlb, cnt, abuf);
    gemm_out<<<dim3(16, 32), 256, 0, stream>>>(abuf, Wot, bo, out);
}

// Round 11
// 207.073 us; speedup vs baseline: 1.6552x; 1.6552x over previous
//
#include <hip/hip_runtime.h>
#include <math.h>

typedef short bf16x8 __attribute__((ext_vector_type(8)));
typedef float f32x4  __attribute__((ext_vector_type(4)));

__device__ __forceinline__ unsigned short f2bf(float f) {
    unsigned int u = __builtin_bit_cast(unsigned int, f);
    u += 0x7FFFu + ((u >> 16) & 1u);
    return (unsigned short)(u >> 16);
}
__device__ __forceinline__ float bf2f(unsigned short u) {
    return __builtin_bit_cast(float, (unsigned int)u << 16);
}
// pack two f32 -> two bf16 (truncating) in one v_perm
__device__ __forceinline__ unsigned pktrunc(float hi, float lo) {
    return __builtin_amdgcn_perm(__builtin_bit_cast(unsigned, hi),
                                 __builtin_bit_cast(unsigned, lo), 0x07060302u);
}

// async global->LDS, 16B per lane. LDS dest = wave-uniform base + lane*16;
// source address may be arbitrary per-lane (we exploit this for swizzles).
__device__ __forceinline__ void gld16(const unsigned short* g, unsigned short* l) {
    __builtin_amdgcn_global_load_lds(
        (const __attribute__((address_space(1))) void*)g,
        (__attribute__((address_space(3))) void*)l, 16, 0, 0);
}

#define QSCALE 0.18033688011112042f   // 0.125 * log2(e)

// ---------------------------------------------------------------------------
// prep: fused cast3 + weight transposes (+Wo column permute) + mask pack.
// ---------------------------------------------------------------------------
__global__ __launch_bounds__(256) void prep(
    const float* __restrict__ x, const float* __restrict__ c1, const float* __restrict__ c2,
    const int* __restrict__ mask1, const int* __restrict__ mask2,
    const float* __restrict__ Wq, const float* __restrict__ Wk1, const float* __restrict__ Wk2,
    const float* __restrict__ Wv1, const float* __restrict__ Wv2, const float* __restrict__ Wo,
    unsigned short* __restrict__ xb, unsigned short* __restrict__ c1b, unsigned short* __restrict__ c2b,
    unsigned short* __restrict__ Wqt, unsigned short* __restrict__ Wk1t, unsigned short* __restrict__ Wk2t,
    unsigned short* __restrict__ Wv1t, unsigned short* __restrict__ Wv2t, unsigned short* __restrict__ Wot,
    unsigned long long* __restrict__ mpk)
{
    __shared__ float T[64][65];
    const int bid = blockIdx.x, t = threadIdx.x;

    if (bid < 3072) {                                   // cast fp32->bf16
        const int z = bid >> 10;
        const float* a = z == 0 ? x : (z == 1 ? c1 : c2);
        unsigned short* o = z == 0 ? xb : (z == 1 ? c1b : c2b);
        size_t i = ((size_t)(bid & 1023) * 256 + t) * 8;
        float4 x0 = *(const float4*)&a[i];
        float4 x1 = *(const float4*)&a[i + 4];
        uint4 pk;
        pk.x = (unsigned)f2bf(x0.x) | ((unsigned)f2bf(x0.y) << 16);
        pk.y = (unsigned)f2bf(x0.z) | ((unsigned)f2bf(x0.w) << 16);
        pk.z = (unsigned)f2bf(x1.x) | ((unsigned)f2bf(x1.y) << 16);
        pk.w = (unsigned)f2bf(x1.z) | ((unsigned)f2bf(x1.w) << 16);
        *(uint4*)&o[i] = pk;
        return;
    }
    if (bid < 4224) {                                   // weight cast+transpose
        const float* W; unsigned short* O; int N, n0, k0; bool perm = false;
        if (bid < 3456) {
            int l = bid - 3072, z = l >> 7, rem = l & 127;
            W = z == 0 ? Wq : (z == 1 ? Wk1 : Wk2);
            O = z == 0 ? Wqt : (z == 1 ? Wk1t : Wk2t);
            N = 512; n0 = (rem & 7) << 6; k0 = (rem >> 3) << 6;
        } else {
            int l = bid - 3456, z = l >> 8, rem = l & 255;
            W = z == 0 ? Wv1 : (z == 1 ? Wv2 : Wo);
            O = z == 0 ? Wv1t : (z == 1 ? Wv2t : Wot);
            N = 1024; n0 = (rem & 15) << 6; k0 = (rem >> 4) << 6;
            perm = (z == 2);
        }
        #pragma unroll
        for (int i = 0; i < 4; i++) {
            int vi = t + (i << 8);
            int r = vi >> 4, c4 = (vi & 15) << 2;
            *(float4*)&T[r][c4] = *(const float4*)&W[(size_t)(k0 + r) * N + n0 + c4];
        }
        __syncthreads();
        #pragma unroll
        for (int i = 0; i < 4; i++) {
            int vi = t + (i << 8);
            int n = vi >> 4, k4 = (vi & 15) << 2;
            if (!perm) {
                uint2 pk;
                pk.x = (unsigned)f2bf(T[k4 + 0][n]) | ((unsigned)f2bf(T[k4 + 1][n]) << 16);
                pk.y = (unsigned)f2bf(T[k4 + 2][n]) | ((unsigned)f2bf(T[k4 + 3][n]) << 16);
                *(uint2*)&O[(size_t)(n0 + n) * 1024 + k0 + k4] = pk;
            } else {
                #pragma unroll
                for (int ii = 0; ii < 4; ii++) {
                    int k = k0 + k4 + ii, f = k & 127;
                    int kp = (k & ~127) | ((f & 15) << 3) | (f >> 4);   // head f-permute
                    O[(size_t)(n0 + n) * 1024 + kp] = f2bf(T[k4 + ii][n]);
                }
            }
        }
        return;
    }
    {                                                   // mask pack
        int wid = ((bid - 4224) << 2) + (t >> 6);
        int lane = t & 63;
        const int* m1 = mask1 + ((size_t)wid << 10);
        const int* m2 = mask2 + ((size_t)wid << 10);
        unsigned long long* o = mpk + ((size_t)wid << 5);
        #pragma unroll
        for (int win = 0; win < 16; win++) {
            unsigned long long bal = __ballot(m1[(win << 6) + lane] != 0);
            if (lane == 0) o[win] = bal;
        }
        #pragma unroll
        for (int win = 0; win < 16; win++) {
            unsigned long long bal = __ballot(m2[(win << 6) + lane] != 0);
            if (lane == 0) o[16 + win] = bal;
        }
    }
}

// ---------------------------------------------------------------------------
// MFMA GEMM core, BK=64, source-permuted gld16 staging (chunk ^= row&7) so
// LDS dest stays linear but frag ds_read_b128s are conflict-free.
// Templated on M-tile / N-tile (waves in 2x2).
// ---------------------------------------------------------------------------
template<int MT, int NT>
__device__ __forceinline__ void gemm_core64(
    const unsigned short* __restrict__ A,
    const unsigned short* __restrict__ Wt,
    int K, int gm0, int gn0,
    unsigned short* As, unsigned short* Bs,
    f32x4 (&acc)[MT / 32][NT / 32])
{
    const int t = threadIdx.x;
    const int lane = t & 63, w = t >> 6;
    const int wm = (w & 1) * (MT / 2), wn = (w >> 1) * (NT / 2);
    const int l15 = lane & 15, quad = lane >> 4;
    const int lrow = lane >> 3, lchk = lane & 7;

    for (int k0 = 0; k0 < K; k0 += 64) {
        __syncthreads();
        #pragma unroll
        for (int i = 0; i < MT / 32; i++) {         // A: MT x 64
            int r0 = w * (MT / 4) + (i << 3);
            int ra = r0 + lrow;
            int kc = (lchk ^ (ra & 7)) << 3;
            gld16(&A[(size_t)(gm0 + ra) * K + k0 + kc], As + (r0 << 6) + (lane << 3));
        }
        #pragma unroll
        for (int i = 0; i < NT / 32; i++) {         // B: NT x 64
            int r0 = w * (NT / 4) + (i << 3);
            int ra = r0 + lrow;
            int kc = (lchk ^ (ra & 7)) << 3;
            gld16(&Wt[(size_t)(gn0 + ra) * K + k0 + kc], Bs + (r0 << 6) + (lane << 3));
        }
        __syncthreads();
        #pragma unroll
        for (int kk = 0; kk < 2; kk++) {
            bf16x8 af[MT / 32], bg[NT / 32];
            #pragma unroll
            for (int i = 0; i < MT / 32; i++) {
                int row = wm + (i << 4) + l15;
                af[i] = *(const bf16x8*)&As[(row << 6) + ((((kk << 2) + quad) ^ (row & 7)) << 3)];
            }
            #pragma unroll
            for (int j = 0; j < NT / 32; j++) {
                int row = wn + (j << 4) + l15;
                bg[j] = *(const bf16x8*)&Bs[(row << 6) + ((((kk << 2) + quad) ^ (row & 7)) << 3)];
            }
            #pragma unroll
            for (int i = 0; i < MT / 32; i++)
                #pragma unroll
                for (int j = 0; j < NT / 32; j++)
                    acc[i][j] = __builtin_amdgcn_mfma_f32_16x16x32_bf16(af[i], bg[j], acc[i][j], 0, 0, 0);
        }
    }
}

// ---------------------------------------------------------------------------
// All 5 projections. qbuf pre-scaled by 0.125*log2e. k/v epilogues transpose
// through LDS so all global stores are coalesced uint4.
// ---------------------------------------------------------------------------
__global__ __launch_bounds__(256) void proj_all(
    const unsigned short* __restrict__ xb, const unsigned short* __restrict__ c1b,
    const unsigned short* __restrict__ c2b,
    const unsigned short* __restrict__ Wqt, const unsigned short* __restrict__ Wk1t,
    const unsigned short* __restrict__ Wk2t, const unsigned short* __restrict__ Wv1t,
    const unsigned short* __restrict__ Wv2t,
    const float* __restrict__ bq, const float* __restrict__ bk1, const float* __restrict__ bk2,
    const float* __restrict__ bv1, const float* __restrict__ bv2,
    unsigned short* __restrict__ qbuf, unsigned short* __restrict__ khb,
    unsigned short* __restrict__ vhb)
{
    __shared__ unsigned short smem[17408];   // As 8192 + Bs 8192; Ts 17408 (union)
    unsigned short* As = smem;
    unsigned short* Bs = smem + 8192;
    unsigned short* Ts = smem;               // [128][136] after core

    const int bid = blockIdx.x;
    int z, bx, by;
    if (bid < 192) { z = bid >> 6; int l = bid & 63; by = l >> 2; bx = l & 3; }
    else { int l = bid - 192; z = 3 + (l >> 7); l &= 127; by = l >> 3; bx = l & 7; }
    const unsigned short* A  = (z == 0) ? xb : (z == 1 || z == 3) ? c1b : c2b;
    const unsigned short* Wt = (z == 0) ? Wqt : (z == 1) ? Wk1t : (z == 2) ? Wk2t
                             : (z == 3) ? Wv1t : Wv2t;
    const float* bias = (z == 0) ? bq : (z == 1) ? bk1 : (z == 2) ? bk2
                      : (z == 3) ? bv1 : bv2;
    const int gm0 = by << 7, gn0 = bx << 7;

    f32x4 acc[4][4];
    #pragma unroll
    for (int i = 0; i < 4; i++)
        #pragma unroll
        for (int j = 0; j < 4; j++) acc[i][j] = (f32x4){0.f, 0.f, 0.f, 0.f};

    gemm_core64<128, 128>(A, Wt, 1024, gm0, gn0, As, Bs, acc);

    const int t = threadIdx.x;
    const int lane = t & 63, w = t >> 6;
    const int wm = (w & 1) << 6, wn = (w >> 1) << 6;
    const int l15 = lane & 15, quad = lane >> 4;
    float bb[4];
    #pragma unroll
    for (int j = 0; j < 4; j++) bb[j] = bias[gn0 + wn + (j << 4) + l15];

    if (z == 0) {                                       // q: row-major, scale baked
        #pragma unroll
        for (int i = 0; i < 4; i++) {
            int mb = gm0 + wm + (i << 4) + (quad << 2);
            #pragma unroll
            for (int p = 0; p < 4; p++)
                #pragma unroll
                for (int j = 0; j < 4; j++)
                    qbuf[(size_t)(mb + p) * 512 + gn0 + wn + (j << 4) + l15]
                        = f2bf((acc[i][j][p] + bb[j]) * QSCALE);
        }
        return;
    }

    __syncthreads();                                    // staging LDS dead -> Ts
    const int b = gm0 >> 10;
    if (z < 3) {                                        // k -> khb[b][h][j][64] swz
        const int jb = ((z == 2) ? 1024 : 0) + (gm0 & 1023);
        #pragma unroll
        for (int i = 0; i < 4; i++) {
            int jl0 = wm + (i << 4) + (quad << 2);
            #pragma unroll
            for (int j = 0; j < 4; j++) {
                int n = wn + (j << 4) + l15;
                #pragma unroll
                for (int p = 0; p < 4; p++)
                    Ts[(jl0 + p) * 136 + n] = f2bf(acc[i][j][p] + bb[j]);
            }
        }
        __syncthreads();
        #pragma unroll
        for (int rr = 0; rr < 8; rr++) {
            int row = (rr << 4) + (t >> 4), cd = t & 15;
            uint4 v = *(const uint4*)&Ts[row * 136 + (cd << 3)];
            int jg = jb + row;
            int hcol = (gn0 >> 6) + (cd >> 3);
            size_t hb = ((size_t)((b << 3) + hcol) << 17);
            *(uint4*)&khb[hb + ((size_t)jg << 6) + ((((cd & 7) ^ (jg & 7))) << 3)] = v;
        }
    } else {                                            // v -> vhb[b][h][f][2048] swz
        const int jb = ((z == 3) ? 0 : 1024) + (gm0 & 1023);
        #pragma unroll
        for (int i = 0; i < 4; i++) {
            int jl0 = wm + (i << 4) + (quad << 2);
            #pragma unroll
            for (int j = 0; j < 4; j++) {
                int n = wn + (j << 4) + l15;
                unsigned long long pk = 0;
                #pragma unroll
                for (int p = 0; p < 4; p++)
                    pk |= (unsigned long long)f2bf(acc[i][j][p] + bb[j]) << (16 * p);
                *(unsigned long long*)&Ts[n * 136 + jl0] = pk;
            }
        }
        __syncthreads();
        const int hv = gn0 >> 7;
        size_t hbase = ((size_t)((b << 3) + hv) << 18);
        #pragma unroll
        for (int rr = 0; rr < 8; rr++) {
            int f = (rr << 4) + (t >> 4), cj = t & 15;
            uint4 v = *(const uint4*)&Ts[f * 136 + (cj << 3)];
            int jj = jb + (cj << 3);
            int jpos = (jj & ~63) | ((((jj >> 3) & 7) ^ (f & 7)) << 3);
            *(uint4*)&vhb[hbase + ((size_t)f << 11) + jpos] = v;
        }
    }
}

// ---------------------------------------------------------------------------
// final: out = abuf(bf16, f'-permuted cols) @ Wot(perm-baked)^T + bo, fp32.
// 64x64 tiles -> 512 blocks = 2 blocks/CU.
// ---------------------------------------------------------------------------
__global__ __launch_bounds__(256) void gemm_out(
    const unsigned short* __restrict__ abuf, const unsigned short* __restrict__ Wot,
    const float* __restrict__ bo, float* __restrict__ out)
{
    __shared__ unsigned short smem[8192];    // As 4096 + Bs 4096
    unsigned short* As = smem;
    unsigned short* Bs = smem + 4096;
    const int gm0 = blockIdx.y << 6, gn0 = blockIdx.x << 6;

    f32x4 acc[2][2];
    #pragma unroll
    for (int i = 0; i < 2; i++)
        #pragma unroll
        for (int j = 0; j < 2; j++) acc[i][j] = (f32x4){0.f, 0.f, 0.f, 0.f};

    gemm_core64<64, 64>(abuf, Wot, 1024, gm0, gn0, As, Bs, acc);

    const int lane = threadIdx.x & 63, w = threadIdx.x >> 6;
    const int wm = (w & 1) << 5, wn = (w >> 1) << 5;
    const int l15 = lane & 15, quad = lane >> 4;
    float bb[2];
    #pragma unroll
    for (int j = 0; j < 2; j++) bb[j] = bo[gn0 + wn + (j << 4) + l15];
    #pragma unroll
    for (int i = 0; i < 2; i++) {
        int mb = gm0 + wm + (i << 4) + (quad << 2);
        #pragma unroll
        for (int p = 0; p < 4; p++)
            #pragma unroll
            for (int j = 0; j < 2; j++)
                out[(size_t)(mb + p) * 1024 + gn0 + wn + (j << 4) + l15] = acc[i][j][p] + bb[j];
    }
}

// ---------------------------------------------------------------------------
// MFMA flash attention (r9 structure — separate combine dispatch; NO fences,
// NO device-scope handoff: cross-XCD L2 writeback/invalidate from in-kernel
// threadfence thrashed L2 in r8/r10). 1024 blocks = (jsplit4, b, qt16, h).
// ---------------------------------------------------------------------------
__global__ __launch_bounds__(256) void attn_mfma(
    const unsigned short* __restrict__ qbuf, const unsigned short* __restrict__ khb,
    const unsigned short* __restrict__ vhb, const unsigned long long* __restrict__ mpk,
    unsigned short* __restrict__ Opart, float* __restrict__ ml)
{
    __shared__ unsigned short Ks[64 * 64];     // 8 KB
    __shared__ unsigned short VsT[128 * 64];   // 16 KB
    __shared__ unsigned short Ps[64 * 64];     // 8 KB

    const int t = threadIdx.x;
    const int bid = blockIdx.x;
    const int hs = bid >> 8, r = bid & 255;
    const int h = r & 7, qt = (r >> 3) & 15, b = r >> 7;
    const int q0 = qt << 6;
    const int lane = t & 63, w = t >> 6, l15 = lane & 15, quad = lane >> 4;
    const int v7 = l15 & 7;

    const unsigned short* qrow = qbuf + (((size_t)(b << 10) + q0 + (w << 4) + l15) << 9) + (h << 6);
    const bf16x8 aq0 = *(const bf16x8*)&qrow[quad << 3];
    const bf16x8 aq1 = *(const bf16x8*)&qrow[32 + (quad << 3)];

    f32x4 acc[8];
    #pragma unroll
    for (int ct = 0; ct < 8; ct++) acc[ct] = (f32x4){0.f, 0.f, 0.f, 0.f};
    float m_l = -3.0e38f, l_l = 0.f;

    const unsigned short* kh = khb + ((size_t)((b << 3) + h) << 17);
    const unsigned short* vh = vhb + ((size_t)((b << 3) + h) << 18);
    const unsigned long long* mrow = mpk + (((size_t)(b << 10) + q0 + (w << 4) + l15) << 5) + (hs << 3);
    const int prow = ((w << 4) + l15) << 6;

    for (int jt = 0; jt < 8; jt++) {
        const int j0 = (hs << 9) + (jt << 6);
        __syncthreads();
        {   // K tile: 8KB contiguous
            const unsigned short* kg = kh + ((size_t)j0 << 6);
            int o = (w << 10) + (lane << 3);
            gld16(kg + o, Ks + o);
            gld16(kg + o + 512, Ks + o + 512);
        }
        #pragma unroll
        for (int it = 0; it < 4; it++) {    // V tile: 128f x 64j
            int f0 = (w << 5) + (it << 3);
            gld16(vh + ((size_t)(f0 + (lane >> 3)) << 11) + j0 + ((lane & 7) << 3),
                  VsT + (f0 << 6) + (lane << 3));
        }
        __syncthreads();

        const unsigned long long mw = mrow[jt];

        // S^T = K Q^T (base-2 domain; scale baked in qbuf)
        f32x4 s[4];
        #pragma unroll
        for (int n = 0; n < 4; n++) {
            int rowk = (n << 4) + l15;
            bf16x8 bk0 = *(const bf16x8*)&Ks[(rowk << 6) + ((quad ^ v7) << 3)];
            bf16x8 bk1 = *(const bf16x8*)&Ks[(rowk << 6) + (((quad + 4) ^ v7) << 3)];
            s[n] = (f32x4){0.f, 0.f, 0.f, 0.f};
            s[n] = __builtin_amdgcn_mfma_f32_16x16x32_bf16(bk0, aq0, s[n], 0, 0, 0);
            s[n] = __builtin_amdgcn_mfma_f32_16x16x32_bf16(bk1, aq1, s[n], 0, 0, 0);
        }
        #pragma unroll
        for (int n = 0; n < 4; n++)
            #pragma unroll
            for (int p = 0; p < 4; p++)
                s[n][p] = ((mw >> ((n << 4) + (quad << 2) + p)) & 1ull) ? s[n][p] : -3.0e38f;

        float mt = s[0][0];
        #pragma unroll
        for (int n = 0; n < 4; n++)
            #pragma unroll
            for (int p = 0; p < 4; p++) mt = fmaxf(mt, s[n][p]);
        mt = fmaxf(mt, __shfl_xor(mt, 16, 64));
        mt = fmaxf(mt, __shfl_xor(mt, 32, 64));
        float mn = fmaxf(m_l, mt);
        float ls = 0.f;
        #pragma unroll
        for (int n = 0; n < 4; n++) {
            float e0 = __builtin_amdgcn_exp2f(s[n][0] - mn);
            float e1 = __builtin_amdgcn_exp2f(s[n][1] - mn);
            float e2 = __builtin_amdgcn_exp2f(s[n][2] - mn);
            float e3 = __builtin_amdgcn_exp2f(s[n][3] - mn);
            ls += (e0 + e1) + (e2 + e3);
            uint2 pk;
            pk.x = pktrunc(e1, e0);
            pk.y = pktrunc(e3, e2);
            int mblk = ((n << 1) + (quad >> 1)) ^ v7;
            *(uint2*)&Ps[prow + (mblk << 3) + ((quad & 1) << 2)] = pk;
        }
        ls += __shfl_xor(ls, 16, 64);
        ls += __shfl_xor(ls, 32, 64);
        float al = __builtin_amdgcn_exp2f(m_l - mn);
        l_l = l_l * al + ls;
        m_l = mn;

        float ar[4];
        #pragma unroll
        for (int p = 0; p < 4; p++)
            ar[p] = __shfl(al, (lane & 48) | ((quad << 2) + p), 64);
        #pragma unroll
        for (int ct = 0; ct < 8; ct++)
            #pragma unroll
            for (int p = 0; p < 4; p++) acc[ct][p] *= ar[p];

        // O += P V
        bf16x8 ap[2];
        #pragma unroll
        for (int win = 0; win < 2; win++) {
            int mblk = ((win << 2) + quad) ^ v7;
            ap[win] = *(const bf16x8*)&Ps[prow + (mblk << 3)];
        }
        #pragma unroll
        for (int ct = 0; ct < 8; ct++) {
            int f = (ct << 4) + l15;
            #pragma unroll
            for (int win = 0; win < 2; win++) {
                int c = (win << 2) + quad;
                bf16x8 bv = *(const bf16x8*)&VsT[(f << 6) + ((c ^ v7) << 3)];
                acc[ct] = __builtin_amdgcn_mfma_f32_16x16x32_bf16(ap[win], bv, acc[ct], 0, 0, 0);
            }
        }
    }

    #pragma unroll
    for (int p = 0; p < 4; p++) {
        int q = q0 + (w << 4) + (quad << 2) + p;
        size_t idx = ((size_t)hs << 14) + ((size_t)((b << 3) + h) << 10) + q;
        uint4 pk;
        pk.x = (unsigned)f2bf(acc[0][p]) | ((unsigned)f2bf(acc[1][p]) << 16);
        pk.y = (unsigned)f2bf(acc[2][p]) | ((unsigned)f2bf(acc[3][p]) << 16);
        pk.z = (unsigned)f2bf(acc[4][p]) | ((unsigned)f2bf(acc[5][p]) << 16);
        pk.w = (unsigned)f2bf(acc[6][p]) | ((unsigned)f2bf(acc[7][p]) << 16);
        *(uint4*)&Opart[(idx << 7) + (l15 << 3)] = pk;
    }
    if (quad == 0) {
        int q = q0 + (w << 4) + l15;
        size_t idx = ((size_t)hs << 14) + ((size_t)((b << 3) + h) << 10) + q;
        ml[(idx << 1) + 0] = m_l;
        ml[(idx << 1) + 1] = l_l;
    }
}

// ---------------------------------------------------------------------------
// Combine 4 j-split partials -> abuf bf16 (f'-permuted cols). Base-2 domain.
// ---------------------------------------------------------------------------
__global__ __launch_bounds__(256) void attn_combine(
    const unsigned short* __restrict__ Opart, const float* __restrict__ ml,
    unsigned short* __restrict__ abuf)
{
    int id = (blockIdx.x << 8) + threadIdx.x;          // 524288
    int bhq = id >> 5, c = id & 31;
    float2 m0 = ((const float2*)ml)[bhq];
    float2 m1 = ((const float2*)ml)[16384 + bhq];
    float2 m2 = ((const float2*)ml)[32768 + bhq];
    float2 m3 = ((const float2*)ml)[49152 + bhq];
    float M = fmaxf(fmaxf(m0.x, m1.x), fmaxf(m2.x, m3.x));
    float a0 = __builtin_amdgcn_exp2f(m0.x - M), a1 = __builtin_amdgcn_exp2f(m1.x - M);
    float a2 = __builtin_amdgcn_exp2f(m2.x - M), a3 = __builtin_amdgcn_exp2f(m3.x - M);
    float inv = 1.0f / (m0.y * a0 + m1.y * a1 + m2.y * a2 + m3.y * a3);
    a0 *= inv; a1 *= inv; a2 *= inv; a3 *= inv;
    float o[4] = {0.f, 0.f, 0.f, 0.f};
    float as[4] = {a0, a1, a2, a3};
    #pragma unroll
    for (int s = 0; s < 4; s++) {
        uint2 v = *(const uint2*)&Opart[((size_t)(s * 16384 + bhq) << 7) + (c << 2)];
        o[0] += as[s] * bf2f((unsigned short)(v.x & 0xFFFF));
        o[1] += as[s] * bf2f((unsigned short)(v.x >> 16));
        o[2] += as[s] * bf2f((unsigned short)(v.y & 0xFFFF));
        o[3] += as[s] * bf2f((unsigned short)(v.y >> 16));
    }
    int b = bhq >> 13, hh = (bhq >> 10) & 7, q = bhq & 1023;
    unsigned long long pk = (unsigned long long)f2bf(o[0])
        | ((unsigned long long)f2bf(o[1]) << 16)
        | ((unsigned long long)f2bf(o[2]) << 32)
        | ((unsigned long long)f2bf(o[3]) << 48);
    *(unsigned long long*)&abuf[((size_t)((b << 10) + q) << 10) + (hh << 7) + (c << 2)] = pk;
}

// ---------------------------------------------------------------------------
extern "C" void kernel_launch(void* const* d_in, const int* in_sizes, int n_in,
                              void* d_out, int out_size, void* d_ws, size_t ws_size,
                              hipStream_t stream)
{
    const float* x        = (const float*)d_in[0];
    const float* context  = (const float*)d_in[1];
    const float* context2 = (const float*)d_in[2];
    const int*   mask1    = (const int*)d_in[3];
    const int*   mask2    = (const int*)d_in[4];
    const float* Wq  = (const float*)d_in[5];
    const float* bq  = (const float*)d_in[6];
    const float* Wk1 = (const float*)d_in[7];
    const float* bk1 = (const float*)d_in[8];
    const float* Wv1 = (const float*)d_in[9];
    const float* bv1 = (const float*)d_in[10];
    const float* Wk2 = (const float*)d_in[11];
    const float* bk2 = (const float*)d_in[12];
    const float* Wv2 = (const float*)d_in[13];
    const float* bv2 = (const float*)d_in[14];
    const float* Wo  = (const float*)d_in[15];
    const float* bo  = (const float*)d_in[16];
    float* out = (float*)d_out;

    // Workspace (MB): Wot[0,2) xb[2,6) c1b[6,10) c2b[10,14) Wqt[14,15)
    // Wk1t[15,16) Wk2t[16,17) Wv1t[17,19) Wv2t[19,21) qbuf[21,23) khb[23,27)
    // vhb[27,35) mpk[35,35.5) mlb[35.5,36).
    // Post-proj overlap: Opart[2,18), abuf[19,23).
    char* W = (char*)d_ws;
    unsigned short* Wot  = (unsigned short*)(W);
    unsigned short* xb   = (unsigned short*)(W + (2ull  << 20));
    unsigned short* c1b  = (unsigned short*)(W + (6ull  << 20));
    unsigned short* c2b  = (unsigned short*)(W + (10ull << 20));
    unsigned short* Wqt  = (unsigned short*)(W + (14ull << 20));
    unsigned short* Wk1t = (unsigned short*)(W + (15ull << 20));
    unsigned short* Wk2t = (unsigned short*)(W + (16ull << 20));
    unsigned short* Wv1t = (unsigned short*)(W + (17ull << 20));
    unsigned short* Wv2t = (unsigned short*)(W + (19ull << 20));
    unsigned short* qbuf = (unsigned short*)(W + (21ull << 20));
    unsigned short* khb  = (unsigned short*)(W + (23ull << 20));
    unsigned short* vhb  = (unsigned short*)(W + (27ull << 20));
    unsigned long long* mpk = (unsigned long long*)(W + (35ull << 20));
    float*          mlb  = (float*)(W + (35ull << 20) + (1ull << 19));
    unsigned short* Opart = (unsigned short*)(W + (2ull << 20));
    unsigned short* abuf  = (unsigned short*)(W + (19ull << 20));

    prep<<<dim3(4736), 256, 0, stream>>>(x, context, context2, mask1, mask2,
                                         Wq, Wk1, Wk2, Wv1, Wv2, Wo,
                                         xb, c1b, c2b, Wqt, Wk1t, Wk2t, Wv1t, Wv2t, Wot, mpk);
    proj_all<<<dim3(448), 256, 0, stream>>>(xb, c1b, c2b, Wqt, Wk1t, Wk2t, Wv1t, Wv2t,
                                            bq, bk1, bk2, bv1, bv2, qbuf, khb, vhb);
    attn_mfma<<<dim3(1024), 256, 0, stream>>>(qbuf, khb, vhb, mpk, Opart, mlb);
    attn_combine<<<dim3(2048), 256, 0, stream>>>(Opart, mlb, abuf);
    gemm_out<<<dim3(16, 32), 256, 0, stream>>>(abuf, Wot, bo, out);
}